// Round 8
// baseline (366.476 us; speedup 1.0000x reference)
//
#include <hip/hip_runtime.h>
#include <math.h>

#define B_  4
#define T_  288
#define N_  207
#define D_  152
#define FF_ 256
#define ND_ (N_*D_)      // 31464, divisible by 4
#define ND4 (ND_/4)      // 7866
#define K_  6
#define TK_ (T_*K_)      // 1728
#define NXCD 8
#define CPX (TK_/NXCD)   // 216 blocks per XCD chunk (exact)

// native clang vector type — accepted by __builtin_nontemporal_load/store
typedef float vfloat4 __attribute__((ext_vector_type(4)));

// ---------------- kernel 1a: column sums of Wq / Wk ----------------
__global__ void colsum_kernel(const float* __restrict__ Wq,
                              const float* __restrict__ Wk,
                              float* __restrict__ wq_sum,
                              float* __restrict__ wk_sum) {
    int j = blockIdx.x * blockDim.x + threadIdx.x;   // float4 index
    if (j >= ND4) return;
    const vfloat4* W  = (const vfloat4*)((blockIdx.y == 0) ? Wq : Wk);
    vfloat4*      out = (vfloat4*)((blockIdx.y == 0) ? wq_sum : wk_sum);
    vfloat4 s = {0.f, 0.f, 0.f, 0.f};
    #pragma unroll 4
    for (int ff = 0; ff < FF_; ++ff)
        s += __builtin_nontemporal_load(&W[(size_t)ff * ND4 + j]);
    out[j] = s;
}

// ---------------- kernel 1b: bias sums ----------------
__global__ void biassum_kernel(const float* __restrict__ bq,
                               const float* __restrict__ bk,
                               float* __restrict__ bsum) {
    __shared__ float shq[256], shk[256];
    int tid = threadIdx.x;
    shq[tid] = bq[tid];
    shk[tid] = bk[tid];
    __syncthreads();
    for (int s = 128; s > 0; s >>= 1) {
        if (tid < s) { shq[tid] += shq[tid + s]; shk[tid] += shk[tid + s]; }
        __syncthreads();
    }
    if (tid == 0) { bsum[0] = shq[0]; bsum[1] = shk[0]; }
}

// ---------------- kernel 2: sq[b,t], sk[b,t] dual dot ----------------
__global__ void rowdot_kernel(const float* __restrict__ X,
                              const float* __restrict__ wq_sum,
                              const float* __restrict__ wk_sum,
                              const float* __restrict__ bsum,
                              float* __restrict__ sq,
                              float* __restrict__ sk,
                              int*   __restrict__ cnt) {
    int row = blockIdx.x;                  // b*T_ + t, 0..1151
    int tid = threadIdx.x;
    if (row < T_ && tid == 0) cnt[row] = 0;
    const vfloat4* x4 = (const vfloat4*)(X + (size_t)row * ND_);
    const vfloat4* q4 = (const vfloat4*)wq_sum;
    const vfloat4* k4 = (const vfloat4*)wk_sum;
    float pq = 0.f, pk = 0.f;
    for (int j = tid; j < ND4; j += 256) {
        vfloat4 xv = x4[j];
        vfloat4 qv = q4[j];
        vfloat4 kv = k4[j];
        pq += xv.x*qv.x + xv.y*qv.y + xv.z*qv.z + xv.w*qv.w;
        pk += xv.x*kv.x + xv.y*kv.y + xv.z*kv.z + xv.w*kv.w;
    }
    __shared__ float shq[256], shk[256];
    shq[tid] = pq; shk[tid] = pk;
    __syncthreads();
    for (int s = 128; s > 0; s >>= 1) {
        if (tid < s) { shq[tid] += shq[tid + s]; shk[tid] += shk[tid + s]; }
        __syncthreads();
    }
    if (tid == 0) {
        sq[row] = shq[0] + bsum[0];
        sk[row] = shk[0] + bsum[1];
    }
}

// ---------------- kernel 3: per-row top-K + inverse index ----------------
#define SLOTS 5
__global__ __launch_bounds__(64) void topk_kernel(
                            const float* __restrict__ sq,
                            const float* __restrict__ sk,
                            float* __restrict__ out_vals,   // [T_][K_]
                            float* __restrict__ out_idx_f,  // [T_][K_]
                            int*   __restrict__ cnt,        // [T_]
                            int*   __restrict__ lists) {    // [T_][T_]
    int t1   = blockIdx.x;
    int lane = threadIdx.x;
    float sq0 = sq[0*T_ + t1], sq1 = sq[1*T_ + t1];
    float sq2 = sq[2*T_ + t1], sq3 = sq[3*T_ + t1];

    float v[SLOTS]; int vi[SLOTS];
    #pragma unroll
    for (int s = 0; s < SLOTS; ++s) {
        int t2 = lane + s * 64;
        if (t2 < T_ && t2 != t1) {
            float c = sq0*sk[0*T_ + t2] + sq1*sk[1*T_ + t2]
                    + sq2*sk[2*T_ + t2] + sq3*sk[3*T_ + t2];
            v[s]  = c * (1.0f / (129.0f * (float)B_));
            vi[s] = t2;
        } else {
            v[s]  = -INFINITY;
            vi[s] = 0x7fffffff;
        }
    }

    float tv[K_]; int ti[K_];
    for (int k = 0; k < K_; ++k) {
        float bv = v[0]; int bi = vi[0];
        #pragma unroll
        for (int s = 1; s < SLOTS; ++s) {
            if (v[s] > bv || (v[s] == bv && vi[s] < bi)) { bv = v[s]; bi = vi[s]; }
        }
        #pragma unroll
        for (int off = 32; off > 0; off >>= 1) {
            float ov = __shfl_xor(bv, off);
            int   oi = __shfl_xor(bi, off);
            if (ov > bv || (ov == bv && oi < bi)) { bv = ov; bi = oi; }
        }
        tv[k] = bv; ti[k] = bi;
        #pragma unroll
        for (int s = 0; s < SLOTS; ++s)
            if (vi[s] == bi) { v[s] = -INFINITY; vi[s] = 0x7fffffff; }
    }

    if (lane == 0) {
        for (int a = 1; a < K_; ++a) {
            float vv = tv[a]; int ii = ti[a]; int b = a - 1;
            while (b >= 0 && ti[b] > ii) { tv[b+1] = tv[b]; ti[b+1] = ti[b]; --b; }
            tv[b+1] = vv; ti[b+1] = ii;
        }
        for (int k = 0; k < K_; ++k) {
            out_vals [t1*K_ + k] = tv[k];
            out_idx_f[t1*K_ + k] = (float)ti[k];
            int src = ti[k];
            int pos = atomicAdd(&cnt[src], 1);
            lists[src * T_ + pos] = t1 * K_ + k;   // rk of this output row
        }
    }
}

// ---------------- kernel 3b: order outputs by source ----------------
__global__ __launch_bounds__(320) void order_kernel(
                            const int* __restrict__ cnt,
                            const int* __restrict__ lists,
                            int* __restrict__ prefix,      // [T_+1]
                            int* __restrict__ order,       // [TK_]
                            int* __restrict__ srcof) {     // [TK_]
    int tid = threadIdx.x;
    if (tid == 0) {
        int acc = 0;
        for (int s = 0; s < T_; ++s) { prefix[s] = acc; acc += cnt[s]; }
        prefix[T_] = acc;   // == TK_
    }
    __syncthreads();
    if (tid < T_) {
        int base = prefix[tid];
        int n    = cnt[tid];
        for (int e = 0; e < n; ++e) {
            order[base + e] = lists[tid * T_ + e];
            srcof[base + e] = tid;
        }
    }
}

// ---------------- kernel 4: XCD-swizzled balanced gather, NORMAL stores ----
// Single-variable test vs R7: plain stores instead of NT. Full-line normal
// writes avoid RFO (harness fill: 6.8 TB/s, FETCH~0) and the L2 write stream
// streams through while the ~2.7 MB read window (21 rows/XCD) is re-touched
// within microseconds by the ~6 same-src blocks on the same XCD.
__global__ __launch_bounds__(512) void gather_kernel(
                              const float* __restrict__ X,
                              const int* __restrict__ order,
                              const int* __restrict__ srcof,
                              float* __restrict__ out3) {
    int bid = blockIdx.x;                 // 0..TK_-1 (launch order)
    int b   = blockIdx.y;                 // 0..B_-1
    int p   = (bid % NXCD) * CPX + bid / NXCD;   // XCD-chunked, bijective
    int rk  = order[p];
    int src = srcof[p];
    const vfloat4* srcp = (const vfloat4*)(X + ((size_t)b * T_ + src) * ND_);
    vfloat4*       dst  = (vfloat4*)(out3 + ((size_t)b * TK_ + rk) * ND_);
    for (int j = threadIdx.x; j < ND4; j += 512) {
        dst[j] = srcp[j];
    }
}

extern "C" void kernel_launch(void* const* d_in, const int* in_sizes, int n_in,
                              void* d_out, int out_size, void* d_ws, size_t ws_size,
                              hipStream_t stream) {
    const float* X  = (const float*)d_in[0];
    const float* Wq = (const float*)d_in[1];
    const float* bq = (const float*)d_in[2];
    const float* Wk = (const float*)d_in[3];
    const float* bk = (const float*)d_in[4];
    // d_in[5] = K (constant 6, compiled in)

    float* ws = (float*)d_ws;
    float* wq_sum = ws;                       // ND_ floats (16B aligned)
    float* wk_sum = ws + ND_;                 // ND_ floats
    float* bsum   = ws + 2*ND_;               // 2 floats (pad to 4)
    float* sq     = ws + 2*ND_ + 4;           // B_*T_ = 1152
    float* sk     = sq + B_*T_;               // 1152
    int*   cnt    = (int*)(sk + B_*T_);       // T_ ints
    int*   lists  = cnt + T_;                 // T_*T_ ints (82944)
    int*   prefix = lists + T_*T_;            // T_+1 ints
    int*   order  = prefix + T_ + 1;          // TK_ ints
    int*   srcof  = order + TK_;              // TK_ ints

    float* out_vals  = (float*)d_out;                 // 1728
    float* out_idx_f = out_vals + TK_;                // 1728
    float* out3      = out_idx_f + TK_;               // 4*288*6*31464

    dim3 g1((ND4 + 255)/256, 2);
    colsum_kernel<<<g1, 256, 0, stream>>>(Wq, Wk, wq_sum, wk_sum);
    biassum_kernel<<<1, 256, 0, stream>>>(bq, bk, bsum);
    rowdot_kernel<<<B_*T_, 256, 0, stream>>>(X, wq_sum, wk_sum, bsum, sq, sk, cnt);
    topk_kernel<<<T_, 64, 0, stream>>>(sq, sk, out_vals, out_idx_f, cnt, lists);
    order_kernel<<<1, 320, 0, stream>>>(cnt, lists, prefix, order, srcof);
    gather_kernel<<<dim3(TK_, B_), 512, 0, stream>>>(X, order, srcof, out3);
}

// Round 9
// 317.349 us; speedup vs baseline: 1.1548x; 1.1548x over previous
//
#include <hip/hip_runtime.h>
#include <math.h>

#define B_  4
#define T_  288
#define N_  207
#define D_  152
#define FF_ 256
#define ND_ (N_*D_)      // 31464, divisible by 4
#define ND4 (ND_/4)      // 7866
#define K_  6
#define TK_ (T_*K_)      // 1728
#define CH_ 8            // chunks per row
#define CHSZ 984         // ceil(ND4/8); last chunk is 978
#define U_  (TK_*CH_)    // 13824 gather units
#define NXCD 8
#define UPX (U_/NXCD)    // 1728 units per XCD chunk (exact)

// native clang vector type — accepted by __builtin_nontemporal_load/store
typedef float vfloat4 __attribute__((ext_vector_type(4)));

// ---------------- kernel 1a: column sums of Wq / Wk ----------------
__global__ void colsum_kernel(const float* __restrict__ Wq,
                              const float* __restrict__ Wk,
                              float* __restrict__ wq_sum,
                              float* __restrict__ wk_sum) {
    int j = blockIdx.x * blockDim.x + threadIdx.x;   // float4 index
    if (j >= ND4) return;
    const vfloat4* W  = (const vfloat4*)((blockIdx.y == 0) ? Wq : Wk);
    vfloat4*      out = (vfloat4*)((blockIdx.y == 0) ? wq_sum : wk_sum);
    vfloat4 s = {0.f, 0.f, 0.f, 0.f};
    #pragma unroll 4
    for (int ff = 0; ff < FF_; ++ff)
        s += __builtin_nontemporal_load(&W[(size_t)ff * ND4 + j]);
    out[j] = s;
}

// ---------------- kernel 1b: bias sums ----------------
__global__ void biassum_kernel(const float* __restrict__ bq,
                               const float* __restrict__ bk,
                               float* __restrict__ bsum) {
    __shared__ float shq[256], shk[256];
    int tid = threadIdx.x;
    shq[tid] = bq[tid];
    shk[tid] = bk[tid];
    __syncthreads();
    for (int s = 128; s > 0; s >>= 1) {
        if (tid < s) { shq[tid] += shq[tid + s]; shk[tid] += shk[tid + s]; }
        __syncthreads();
    }
    if (tid == 0) { bsum[0] = shq[0]; bsum[1] = shk[0]; }
}

// ---------------- kernel 2: sq[b,t], sk[b,t] dual dot ----------------
__global__ void rowdot_kernel(const float* __restrict__ X,
                              const float* __restrict__ wq_sum,
                              const float* __restrict__ wk_sum,
                              const float* __restrict__ bsum,
                              float* __restrict__ sq,
                              float* __restrict__ sk,
                              int*   __restrict__ cnt) {
    int row = blockIdx.x;                  // b*T_ + t, 0..1151
    int tid = threadIdx.x;
    if (row < T_ && tid == 0) cnt[row] = 0;
    const vfloat4* x4 = (const vfloat4*)(X + (size_t)row * ND_);
    const vfloat4* q4 = (const vfloat4*)wq_sum;
    const vfloat4* k4 = (const vfloat4*)wk_sum;
    float pq = 0.f, pk = 0.f;
    for (int j = tid; j < ND4; j += 256) {
        vfloat4 xv = x4[j];
        vfloat4 qv = q4[j];
        vfloat4 kv = k4[j];
        pq += xv.x*qv.x + xv.y*qv.y + xv.z*qv.z + xv.w*qv.w;
        pk += xv.x*kv.x + xv.y*kv.y + xv.z*kv.z + xv.w*kv.w;
    }
    __shared__ float shq[256], shk[256];
    shq[tid] = pq; shk[tid] = pk;
    __syncthreads();
    for (int s = 128; s > 0; s >>= 1) {
        if (tid < s) { shq[tid] += shq[tid + s]; shk[tid] += shk[tid + s]; }
        __syncthreads();
    }
    if (tid == 0) {
        sq[row] = shq[0] + bsum[0];
        sk[row] = shk[0] + bsum[1];
    }
}

// ---------------- kernel 3: per-row top-K + inverse index ----------------
#define SLOTS 5
__global__ __launch_bounds__(64) void topk_kernel(
                            const float* __restrict__ sq,
                            const float* __restrict__ sk,
                            float* __restrict__ out_vals,   // [T_][K_]
                            float* __restrict__ out_idx_f,  // [T_][K_]
                            int*   __restrict__ cnt,        // [T_]
                            int*   __restrict__ lists) {    // [T_][T_]
    int t1   = blockIdx.x;
    int lane = threadIdx.x;
    float sq0 = sq[0*T_ + t1], sq1 = sq[1*T_ + t1];
    float sq2 = sq[2*T_ + t1], sq3 = sq[3*T_ + t1];

    float v[SLOTS]; int vi[SLOTS];
    #pragma unroll
    for (int s = 0; s < SLOTS; ++s) {
        int t2 = lane + s * 64;
        if (t2 < T_ && t2 != t1) {
            float c = sq0*sk[0*T_ + t2] + sq1*sk[1*T_ + t2]
                    + sq2*sk[2*T_ + t2] + sq3*sk[3*T_ + t2];
            v[s]  = c * (1.0f / (129.0f * (float)B_));
            vi[s] = t2;
        } else {
            v[s]  = -INFINITY;
            vi[s] = 0x7fffffff;
        }
    }

    float tv[K_]; int ti[K_];
    for (int k = 0; k < K_; ++k) {
        float bv = v[0]; int bi = vi[0];
        #pragma unroll
        for (int s = 1; s < SLOTS; ++s) {
            if (v[s] > bv || (v[s] == bv && vi[s] < bi)) { bv = v[s]; bi = vi[s]; }
        }
        #pragma unroll
        for (int off = 32; off > 0; off >>= 1) {
            float ov = __shfl_xor(bv, off);
            int   oi = __shfl_xor(bi, off);
            if (ov > bv || (ov == bv && oi < bi)) { bv = ov; bi = oi; }
        }
        tv[k] = bv; ti[k] = bi;
        #pragma unroll
        for (int s = 0; s < SLOTS; ++s)
            if (vi[s] == bi) { v[s] = -INFINITY; vi[s] = 0x7fffffff; }
    }

    if (lane == 0) {
        for (int a = 1; a < K_; ++a) {
            float vv = tv[a]; int ii = ti[a]; int b = a - 1;
            while (b >= 0 && ti[b] > ii) { tv[b+1] = tv[b]; ti[b+1] = ti[b]; --b; }
            tv[b+1] = vv; ti[b+1] = ii;
        }
        for (int k = 0; k < K_; ++k) {
            out_vals [t1*K_ + k] = tv[k];
            out_idx_f[t1*K_ + k] = (float)ti[k];
            int src = ti[k];
            int pos = atomicAdd(&cnt[src], 1);
            lists[src * T_ + pos] = t1 * K_ + k;   // rk of this output row
        }
    }
}

// ---------------- kernel 3b: build sorted gather units ----------------
// Unit = (dst row rk, src, chunk) packed into one int:
//   bits 0-10 rk (<1728), bits 11-19 src (<288), bits 20-22 chunk (<8).
// Enumerated per src: for c in chunks, for e in dests -> units sharing the
// SAME (src,chunk) 16 KB read are ADJACENT -> dispatched back-to-back on the
// same XCD (after swizzle) -> L2 temporal reuse with ~1-2 us skew.
__global__ __launch_bounds__(320) void order_kernel(
                            const int* __restrict__ cnt,
                            const int* __restrict__ lists,
                            int* __restrict__ prefix,      // [T_+1]
                            int* __restrict__ units) {     // [U_]
    int tid = threadIdx.x;
    if (tid == 0) {
        int acc = 0;
        for (int s = 0; s < T_; ++s) { prefix[s] = acc; acc += cnt[s]; }
        prefix[T_] = acc;   // == TK_
    }
    __syncthreads();
    if (tid < T_) {
        int base = prefix[tid] * CH_;
        int n    = cnt[tid];
        for (int c = 0; c < CH_; ++c) {
            for (int e = 0; e < n; ++e) {
                int rk = lists[tid * T_ + e];
                units[base + c * n + e] = rk | (tid << 11) | (c << 20);
            }
        }
    }
}

// ---------------- kernel 4: chunk-unit gather ----------------
// Block (bid, b): one 15.7 KB chunk-copy. XCD-chunked swizzle puts the ~6
// adjacent same-(src,chunk) units on one XCD; first unit misses to HBM, the
// rest hit that XCD's L2 (NT stores bypass L2, so the chunk survives).
// Predicted HBM: reads ~150-200 MB, writes 870 MB.
__global__ __launch_bounds__(256) void gather_kernel(
                              const float* __restrict__ X,
                              const int* __restrict__ units,
                              float* __restrict__ out3) {
    int bid = blockIdx.x;                 // 0..U_-1 (launch order)
    int b   = blockIdx.y;                 // 0..B_-1
    int p   = (bid % NXCD) * UPX + bid / NXCD;   // XCD-chunked, bijective
    int u   = units[p];
    int rk  = u & 2047;
    int src = (u >> 11) & 511;
    int c   = u >> 20;
    const int j0 = c * CHSZ;
    const int j1 = (j0 + CHSZ < ND4) ? (j0 + CHSZ) : ND4;
    const vfloat4* srcp = (const vfloat4*)(X + ((size_t)b * T_ + src) * ND_);
    vfloat4*       dst  = (vfloat4*)(out3 + ((size_t)b * TK_ + rk) * ND_);
    for (int j = j0 + (int)threadIdx.x; j < j1; j += 256) {
        vfloat4 val = srcp[j];
        __builtin_nontemporal_store(val, &dst[j]);
    }
}

extern "C" void kernel_launch(void* const* d_in, const int* in_sizes, int n_in,
                              void* d_out, int out_size, void* d_ws, size_t ws_size,
                              hipStream_t stream) {
    const float* X  = (const float*)d_in[0];
    const float* Wq = (const float*)d_in[1];
    const float* bq = (const float*)d_in[2];
    const float* Wk = (const float*)d_in[3];
    const float* bk = (const float*)d_in[4];
    // d_in[5] = K (constant 6, compiled in)

    float* ws = (float*)d_ws;
    float* wq_sum = ws;                       // ND_ floats (16B aligned)
    float* wk_sum = ws + ND_;                 // ND_ floats
    float* bsum   = ws + 2*ND_;               // 2 floats (pad to 4)
    float* sq     = ws + 2*ND_ + 4;           // B_*T_ = 1152
    float* sk     = sq + B_*T_;               // 1152
    int*   cnt    = (int*)(sk + B_*T_);       // T_ ints
    int*   lists  = cnt + T_;                 // T_*T_ ints (82944)
    int*   prefix = lists + T_*T_;            // T_+1 ints
    int*   units  = prefix + T_ + 1;          // U_ ints (13824)

    float* out_vals  = (float*)d_out;                 // 1728
    float* out_idx_f = out_vals + TK_;                // 1728
    float* out3      = out_idx_f + TK_;               // 4*288*6*31464

    dim3 g1((ND4 + 255)/256, 2);
    colsum_kernel<<<g1, 256, 0, stream>>>(Wq, Wk, wq_sum, wk_sum);
    biassum_kernel<<<1, 256, 0, stream>>>(bq, bk, bsum);
    rowdot_kernel<<<B_*T_, 256, 0, stream>>>(X, wq_sum, wk_sum, bsum, sq, sk, cnt);
    topk_kernel<<<T_, 64, 0, stream>>>(sq, sk, out_vals, out_idx_f, cnt, lists);
    order_kernel<<<1, 320, 0, stream>>>(cnt, lists, prefix, units);
    gather_kernel<<<dim3(U_, B_), 256, 0, stream>>>(X, units, out3);
}

// Round 10
// 308.705 us; speedup vs baseline: 1.1871x; 1.0280x over previous
//
#include <hip/hip_runtime.h>
#include <math.h>

#define B_  4
#define T_  288
#define N_  207
#define D_  152
#define FF_ 256
#define ND_ (N_*D_)      // 31464, divisible by 4
#define ND4 (ND_/4)      // 7866
#define K_  6
#define TK_ (T_*K_)      // 1728
#define CH_ 8            // chunks per row
#define CHSZ 984         // ceil(ND4/8); last chunk is 978
#define G_  6            // max dests per gather unit (register fan-out)
#define UMAX 576         // Σ ceil(n/G) <= TK_/G + T_ = 288+288

// native clang vector type — accepted by __builtin_nontemporal_load/store
typedef float vfloat4 __attribute__((ext_vector_type(4)));

// ---------------- kernel 1a: column sums of Wq / Wk ----------------
__global__ void colsum_kernel(const float* __restrict__ Wq,
                              const float* __restrict__ Wk,
                              float* __restrict__ wq_sum,
                              float* __restrict__ wk_sum) {
    int j = blockIdx.x * blockDim.x + threadIdx.x;   // float4 index
    if (j >= ND4) return;
    const vfloat4* W  = (const vfloat4*)((blockIdx.y == 0) ? Wq : Wk);
    vfloat4*      out = (vfloat4*)((blockIdx.y == 0) ? wq_sum : wk_sum);
    vfloat4 s = {0.f, 0.f, 0.f, 0.f};
    #pragma unroll 4
    for (int ff = 0; ff < FF_; ++ff)
        s += __builtin_nontemporal_load(&W[(size_t)ff * ND4 + j]);
    out[j] = s;
}

// ---------------- kernel 1b: bias sums ----------------
__global__ void biassum_kernel(const float* __restrict__ bq,
                               const float* __restrict__ bk,
                               float* __restrict__ bsum) {
    __shared__ float shq[256], shk[256];
    int tid = threadIdx.x;
    shq[tid] = bq[tid];
    shk[tid] = bk[tid];
    __syncthreads();
    for (int s = 128; s > 0; s >>= 1) {
        if (tid < s) { shq[tid] += shq[tid + s]; shk[tid] += shk[tid + s]; }
        __syncthreads();
    }
    if (tid == 0) { bsum[0] = shq[0]; bsum[1] = shk[0]; }
}

// ---------------- kernel 2: sq[b,t], sk[b,t] dual dot ----------------
__global__ void rowdot_kernel(const float* __restrict__ X,
                              const float* __restrict__ wq_sum,
                              const float* __restrict__ wk_sum,
                              const float* __restrict__ bsum,
                              float* __restrict__ sq,
                              float* __restrict__ sk,
                              int*   __restrict__ cnt) {
    int row = blockIdx.x;                  // b*T_ + t, 0..1151
    int tid = threadIdx.x;
    if (row < T_ && tid == 0) cnt[row] = 0;
    const vfloat4* x4 = (const vfloat4*)(X + (size_t)row * ND_);
    const vfloat4* q4 = (const vfloat4*)wq_sum;
    const vfloat4* k4 = (const vfloat4*)wk_sum;
    float pq = 0.f, pk = 0.f;
    for (int j = tid; j < ND4; j += 256) {
        vfloat4 xv = x4[j];
        vfloat4 qv = q4[j];
        vfloat4 kv = k4[j];
        pq += xv.x*qv.x + xv.y*qv.y + xv.z*qv.z + xv.w*qv.w;
        pk += xv.x*kv.x + xv.y*kv.y + xv.z*kv.z + xv.w*kv.w;
    }
    __shared__ float shq[256], shk[256];
    shq[tid] = pq; shk[tid] = pk;
    __syncthreads();
    for (int s = 128; s > 0; s >>= 1) {
        if (tid < s) { shq[tid] += shq[tid + s]; shk[tid] += shk[tid + s]; }
        __syncthreads();
    }
    if (tid == 0) {
        sq[row] = shq[0] + bsum[0];
        sk[row] = shk[0] + bsum[1];
    }
}

// ---------------- kernel 3: per-row top-K + inverse index ----------------
#define SLOTS 5
__global__ __launch_bounds__(64) void topk_kernel(
                            const float* __restrict__ sq,
                            const float* __restrict__ sk,
                            float* __restrict__ out_vals,   // [T_][K_]
                            float* __restrict__ out_idx_f,  // [T_][K_]
                            int*   __restrict__ cnt,        // [T_]
                            int*   __restrict__ lists) {    // [T_][T_]
    int t1   = blockIdx.x;
    int lane = threadIdx.x;
    float sq0 = sq[0*T_ + t1], sq1 = sq[1*T_ + t1];
    float sq2 = sq[2*T_ + t1], sq3 = sq[3*T_ + t1];

    float v[SLOTS]; int vi[SLOTS];
    #pragma unroll
    for (int s = 0; s < SLOTS; ++s) {
        int t2 = lane + s * 64;
        if (t2 < T_ && t2 != t1) {
            float c = sq0*sk[0*T_ + t2] + sq1*sk[1*T_ + t2]
                    + sq2*sk[2*T_ + t2] + sq3*sk[3*T_ + t2];
            v[s]  = c * (1.0f / (129.0f * (float)B_));
            vi[s] = t2;
        } else {
            v[s]  = -INFINITY;
            vi[s] = 0x7fffffff;
        }
    }

    float tv[K_]; int ti[K_];
    for (int k = 0; k < K_; ++k) {
        float bv = v[0]; int bi = vi[0];
        #pragma unroll
        for (int s = 1; s < SLOTS; ++s) {
            if (v[s] > bv || (v[s] == bv && vi[s] < bi)) { bv = v[s]; bi = vi[s]; }
        }
        #pragma unroll
        for (int off = 32; off > 0; off >>= 1) {
            float ov = __shfl_xor(bv, off);
            int   oi = __shfl_xor(bi, off);
            if (ov > bv || (ov == bv && oi < bi)) { bv = ov; bi = oi; }
        }
        tv[k] = bv; ti[k] = bi;
        #pragma unroll
        for (int s = 0; s < SLOTS; ++s)
            if (vi[s] == bi) { v[s] = -INFINITY; vi[s] = 0x7fffffff; }
    }

    if (lane == 0) {
        for (int a = 1; a < K_; ++a) {
            float vv = tv[a]; int ii = ti[a]; int b = a - 1;
            while (b >= 0 && ti[b] > ii) { tv[b+1] = tv[b]; ti[b+1] = ti[b]; --b; }
            tv[b+1] = vv; ti[b+1] = ii;
        }
        for (int k = 0; k < K_; ++k) {
            out_vals [t1*K_ + k] = tv[k];
            out_idx_f[t1*K_ + k] = (float)ti[k];
            int src = ti[k];
            int pos = atomicAdd(&cnt[src], 1);
            lists[src * T_ + pos] = t1 * K_ + k;   // rk of this output row
        }
    }
}

// ---------------- kernel 3b: build bounded-fanout gather units ----------------
// Unit = (src, e_base, ne<=G_) packed: src(9b) | e_base<<9 (9b) | ne<<18 (3b).
// Balanced: each unit reads one chunk once, writes <=6 chunk copies.
__global__ __launch_bounds__(320) void order_kernel(
                            const int* __restrict__ cnt,
                            int* __restrict__ units,       // [UMAX]
                            int* __restrict__ ucount) {    // [1]
    __shared__ int pfx[T_];
    int tid = threadIdx.x;
    if (tid == 0) {
        int acc = 0;
        for (int s = 0; s < T_; ++s) {
            pfx[s] = acc;
            acc += (cnt[s] + G_ - 1) / G_;
        }
        ucount[0] = acc;
    }
    __syncthreads();
    if (tid < T_) {
        int n = cnt[tid];
        int base = pfx[tid];
        int g = 0;
        for (int e = 0; e < n; e += G_, ++g) {
            int ne = (n - e < G_) ? (n - e) : G_;
            units[base + g] = tid | (e << 9) | (ne << 18);
        }
    }
}

// ---------------- kernel 4: register-dedup balanced gather ----------------
// Block (bid, b): ug = bid/8 selects a unit, c = bid%8 the 16 KB chunk.
// Load chunk of X[b][src] ONCE into registers, NT-store to <=6 dests.
// Reads ~870/6 MB by construction (no cache assumptions); writes 870 MB NT.
__global__ __launch_bounds__(256) void gather_kernel(
                              const float* __restrict__ X,
                              const int* __restrict__ units,
                              const int* __restrict__ ucount,
                              const int* __restrict__ lists,
                              float* __restrict__ out3) {
    int bid = blockIdx.x;                 // 0 .. UMAX*CH_-1
    int b   = blockIdx.y;                 // 0..B_-1
    int ug  = bid >> 3;
    int c   = bid & 7;
    if (ug >= ucount[0]) return;
    int u   = units[ug];
    int src = u & 511;
    int e0  = (u >> 9) & 511;
    int ne  = (u >> 18) & 7;
    const int j0 = c * CHSZ;
    const int j1 = (j0 + CHSZ < ND4) ? (j0 + CHSZ) : ND4;
    const vfloat4* srcp = (const vfloat4*)(X + ((size_t)b * T_ + src) * ND_);

    vfloat4 r[4];
    #pragma unroll
    for (int uu = 0; uu < 4; ++uu) {
        int j = j0 + (int)threadIdx.x + uu * 256;
        if (j < j1) r[uu] = srcp[j];
    }
    for (int e = 0; e < ne; ++e) {
        int rk = lists[src * T_ + e0 + e];
        vfloat4* dst = (vfloat4*)(out3 + ((size_t)b * TK_ + rk) * ND_);
        #pragma unroll
        for (int uu = 0; uu < 4; ++uu) {
            int j = j0 + (int)threadIdx.x + uu * 256;
            if (j < j1) __builtin_nontemporal_store(r[uu], &dst[j]);
        }
    }
}

extern "C" void kernel_launch(void* const* d_in, const int* in_sizes, int n_in,
                              void* d_out, int out_size, void* d_ws, size_t ws_size,
                              hipStream_t stream) {
    const float* X  = (const float*)d_in[0];
    const float* Wq = (const float*)d_in[1];
    const float* bq = (const float*)d_in[2];
    const float* Wk = (const float*)d_in[3];
    const float* bk = (const float*)d_in[4];
    // d_in[5] = K (constant 6, compiled in)

    float* ws = (float*)d_ws;
    float* wq_sum = ws;                       // ND_ floats (16B aligned)
    float* wk_sum = ws + ND_;                 // ND_ floats
    float* bsum   = ws + 2*ND_;               // 2 floats (pad to 4)
    float* sq     = ws + 2*ND_ + 4;           // B_*T_ = 1152
    float* sk     = sq + B_*T_;               // 1152
    int*   cnt    = (int*)(sk + B_*T_);       // T_ ints
    int*   lists  = cnt + T_;                 // T_*T_ ints (82944)
    int*   units  = lists + T_*T_;            // UMAX ints
    int*   ucount = units + UMAX;             // 1 int

    float* out_vals  = (float*)d_out;                 // 1728
    float* out_idx_f = out_vals + TK_;                // 1728
    float* out3      = out_idx_f + TK_;               // 4*288*6*31464

    dim3 g1((ND4 + 255)/256, 2);
    colsum_kernel<<<g1, 256, 0, stream>>>(Wq, Wk, wq_sum, wk_sum);
    biassum_kernel<<<1, 256, 0, stream>>>(bq, bk, bsum);
    rowdot_kernel<<<B_*T_, 256, 0, stream>>>(X, wq_sum, wk_sum, bsum, sq, sk, cnt);
    topk_kernel<<<T_, 64, 0, stream>>>(sq, sk, out_vals, out_idx_f, cnt, lists);
    order_kernel<<<1, 320, 0, stream>>>(cnt, units, ucount);
    gather_kernel<<<dim3(UMAX*CH_, B_), 256, 0, stream>>>(X, units, ucount, lists, out3);
}

// Round 11
// 293.023 us; speedup vs baseline: 1.2507x; 1.0535x over previous
//
#include <hip/hip_runtime.h>
#include <math.h>

#define B_  4
#define T_  288
#define N_  207
#define D_  152
#define FF_ 256
#define ND_ (N_*D_)      // 31464, divisible by 4
#define ND4 (ND_/4)      // 7866
#define K_  6
#define TK_ (T_*K_)      // 1728

// native clang vector type — accepted by __builtin_nontemporal_load/store
typedef float vfloat4 __attribute__((ext_vector_type(4)));

// ---------------- kernel 1a: column sums of Wq / Wk ----------------
// NT loads: W (64 MB) is touched exactly once; don't pollute caches.
__global__ void colsum_kernel(const float* __restrict__ Wq,
                              const float* __restrict__ Wk,
                              float* __restrict__ wq_sum,
                              float* __restrict__ wk_sum) {
    int j = blockIdx.x * blockDim.x + threadIdx.x;   // float4 index
    if (j >= ND4) return;
    const vfloat4* W  = (const vfloat4*)((blockIdx.y == 0) ? Wq : Wk);
    vfloat4*      out = (vfloat4*)((blockIdx.y == 0) ? wq_sum : wk_sum);
    vfloat4 s = {0.f, 0.f, 0.f, 0.f};
    #pragma unroll 4
    for (int ff = 0; ff < FF_; ++ff)
        s += __builtin_nontemporal_load(&W[(size_t)ff * ND4 + j]);
    out[j] = s;
}

// ---------------- kernel 1b: bias sums ----------------
__global__ void biassum_kernel(const float* __restrict__ bq,
                               const float* __restrict__ bk,
                               float* __restrict__ bsum) {
    __shared__ float shq[256], shk[256];
    int tid = threadIdx.x;
    shq[tid] = bq[tid];
    shk[tid] = bk[tid];
    __syncthreads();
    for (int s = 128; s > 0; s >>= 1) {
        if (tid < s) { shq[tid] += shq[tid + s]; shk[tid] += shk[tid + s]; }
        __syncthreads();
    }
    if (tid == 0) { bsum[0] = shq[0]; bsum[1] = shk[0]; }
}

// ---------------- kernel 2: sq[b,t], sk[b,t] dual dot ----------------
__global__ void rowdot_kernel(const float* __restrict__ X,
                              const float* __restrict__ wq_sum,
                              const float* __restrict__ wk_sum,
                              const float* __restrict__ bsum,
                              float* __restrict__ sq,
                              float* __restrict__ sk) {
    int row = blockIdx.x;                  // b*T_ + t, 0..1151
    int tid = threadIdx.x;
    const vfloat4* x4 = (const vfloat4*)(X + (size_t)row * ND_);
    const vfloat4* q4 = (const vfloat4*)wq_sum;
    const vfloat4* k4 = (const vfloat4*)wk_sum;
    float pq = 0.f, pk = 0.f;
    for (int j = tid; j < ND4; j += 256) {
        vfloat4 xv = x4[j];
        vfloat4 qv = q4[j];
        vfloat4 kv = k4[j];
        pq += xv.x*qv.x + xv.y*qv.y + xv.z*qv.z + xv.w*qv.w;
        pk += xv.x*kv.x + xv.y*kv.y + xv.z*kv.z + xv.w*kv.w;
    }
    __shared__ float shq[256], shk[256];
    shq[tid] = pq; shk[tid] = pk;
    __syncthreads();
    for (int s = 128; s > 0; s >>= 1) {
        if (tid < s) { shq[tid] += shq[tid + s]; shk[tid] += shk[tid + s]; }
        __syncthreads();
    }
    if (tid == 0) {
        sq[row] = shq[0] + bsum[0];
        sk[row] = shk[0] + bsum[1];
    }
}

// ---------------- kernel 3: per-row top-K, wave-parallel argmax ----------------
// One 64-lane wave per row t1; values in 5 regs/lane; 6 butterfly argmax
// rounds, tie-break -> lowest index (matches lax.top_k).
#define SLOTS 5
__global__ __launch_bounds__(64) void topk_kernel(
                            const float* __restrict__ sq,
                            const float* __restrict__ sk,
                            float* __restrict__ out_vals,   // [T_][K_]
                            float* __restrict__ out_idx_f,  // [T_][K_]
                            int*   __restrict__ out_idx_i) {
    int t1   = blockIdx.x;
    int lane = threadIdx.x;
    float sq0 = sq[0*T_ + t1], sq1 = sq[1*T_ + t1];
    float sq2 = sq[2*T_ + t1], sq3 = sq[3*T_ + t1];

    float v[SLOTS]; int vi[SLOTS];
    #pragma unroll
    for (int s = 0; s < SLOTS; ++s) {
        int t2 = lane + s * 64;
        if (t2 < T_ && t2 != t1) {
            float c = sq0*sk[0*T_ + t2] + sq1*sk[1*T_ + t2]
                    + sq2*sk[2*T_ + t2] + sq3*sk[3*T_ + t2];
            v[s]  = c * (1.0f / (129.0f * (float)B_));
            vi[s] = t2;
        } else {
            v[s]  = -INFINITY;
            vi[s] = 0x7fffffff;
        }
    }

    float tv[K_]; int ti[K_];
    for (int k = 0; k < K_; ++k) {
        float bv = v[0]; int bi = vi[0];
        #pragma unroll
        for (int s = 1; s < SLOTS; ++s) {
            if (v[s] > bv || (v[s] == bv && vi[s] < bi)) { bv = v[s]; bi = vi[s]; }
        }
        #pragma unroll
        for (int off = 32; off > 0; off >>= 1) {
            float ov = __shfl_xor(bv, off);
            int   oi = __shfl_xor(bi, off);
            if (ov > bv || (ov == bv && oi < bi)) { bv = ov; bi = oi; }
        }
        tv[k] = bv; ti[k] = bi;
        #pragma unroll
        for (int s = 0; s < SLOTS; ++s)
            if (vi[s] == bi) { v[s] = -INFINITY; vi[s] = 0x7fffffff; }
    }

    if (lane == 0) {
        for (int a = 1; a < K_; ++a) {
            float vv = tv[a]; int ii = ti[a]; int b = a - 1;
            while (b >= 0 && ti[b] > ii) { tv[b+1] = tv[b]; ti[b+1] = ti[b]; --b; }
            tv[b+1] = vv; ti[b+1] = ii;
        }
        for (int k = 0; k < K_; ++k) {
            out_vals [t1*K_ + k] = tv[k];
            out_idx_f[t1*K_ + k] = (float)ti[k];
            out_idx_i[t1*K_ + k] = ti[k];
        }
    }
}

// ---------------- kernel 4: gather (R3 structure, 4-deep batched) ----------------
// Block (rk, b): copy X[b, idx[rk]] -> out3[b, rk]. Consecutive blocks write
// consecutive 126 KB output rows (sequential HBM write order — measured best).
// NT stores (normal stores measured −25% in this kernel). 4 loads in flight
// per wave before the dependent stores.
__global__ __launch_bounds__(256) void gather_kernel(
                              const float* __restrict__ X,
                              const int* __restrict__ idx,
                              float* __restrict__ out3) {
    int rk = blockIdx.x;                  // 0..TK_-1
    int b  = blockIdx.y;                  // 0..B_-1
    int src_t = idx[rk];
    const vfloat4* srcp = (const vfloat4*)(X + ((size_t)b * T_ + src_t) * ND_);
    vfloat4*       dst  = (vfloat4*)(out3 + ((size_t)b * TK_ + rk) * ND_);
    for (int base = 0; base < ND4; base += 1024) {
        vfloat4 r[4];
        #pragma unroll
        for (int u = 0; u < 4; ++u) {
            int j = base + (int)threadIdx.x + u * 256;
            if (j < ND4) r[u] = srcp[j];
        }
        #pragma unroll
        for (int u = 0; u < 4; ++u) {
            int j = base + (int)threadIdx.x + u * 256;
            if (j < ND4) __builtin_nontemporal_store(r[u], &dst[j]);
        }
    }
}

extern "C" void kernel_launch(void* const* d_in, const int* in_sizes, int n_in,
                              void* d_out, int out_size, void* d_ws, size_t ws_size,
                              hipStream_t stream) {
    const float* X  = (const float*)d_in[0];
    const float* Wq = (const float*)d_in[1];
    const float* bq = (const float*)d_in[2];
    const float* Wk = (const float*)d_in[3];
    const float* bk = (const float*)d_in[4];
    // d_in[5] = K (constant 6, compiled in)

    float* ws = (float*)d_ws;
    float* wq_sum = ws;                       // ND_ floats (16B aligned)
    float* wk_sum = ws + ND_;                 // ND_ floats
    float* bsum   = ws + 2*ND_;               // 2 floats (pad to 4)
    float* sq     = ws + 2*ND_ + 4;           // B_*T_ = 1152
    float* sk     = sq + B_*T_;               // 1152
    int*   idx_i  = (int*)(sk + B_*T_);       // TK_ ints

    float* out_vals  = (float*)d_out;                 // 1728
    float* out_idx_f = out_vals + TK_;                // 1728
    float* out3      = out_idx_f + TK_;               // 4*288*6*31464

    dim3 g1((ND4 + 255)/256, 2);
    colsum_kernel<<<g1, 256, 0, stream>>>(Wq, Wk, wq_sum, wk_sum);
    biassum_kernel<<<1, 256, 0, stream>>>(bq, bk, bsum);
    rowdot_kernel<<<B_*T_, 256, 0, stream>>>(X, wq_sum, wk_sum, bsum, sq, sk);
    topk_kernel<<<T_, 64, 0, stream>>>(sq, sk, out_vals, out_idx_f, idx_i);
    gather_kernel<<<dim3(TK_, B_), 256, 0, stream>>>(X, idx_i, out3);
}